// Round 11
// baseline (281.512 us; speedup 1.0000x reference)
//
#include <hip/hip_runtime.h>

// (B,C,T)=(8,512,1024), H=8, D=64, K=64, REL=129. I/O fp32; internal bf16.
#define B_   8
#define C_   512
#define T_   1024
#define H_   8
#define D_   64
#define K_   64
#define REL_ 129

typedef unsigned short u16;
typedef __attribute__((ext_vector_type(8))) short short8;   // 8 bf16 (4 VGPRs)
typedef __attribute__((ext_vector_type(4))) float f32x4;

__device__ __forceinline__ float b2f(u16 u) {
    return __uint_as_float(((unsigned)u) << 16);
}
__device__ __forceinline__ u16 f2b(float f) {
    unsigned x = __float_as_uint(f);
    x += 0x7fffu + ((x >> 16) & 1u);   // RNE
    return (u16)(x >> 16);
}

// ---------------------------------------------------------------------------
// Kernel 0: all input casts in one launch.
// ---------------------------------------------------------------------------
__global__ __launch_bounds__(256) void cast_all_kernel(
    const float* __restrict__ x,
    const float* __restrict__ Wq, const float* __restrict__ Wk,
    const float* __restrict__ Wv, const float* __restrict__ Wo,
    const float* __restrict__ erk, const float* __restrict__ erv,
    u16* __restrict__ xt, u16* __restrict__ Wh,
    u16* __restrict__ ervt, u16* __restrict__ erkb)
{
    __shared__ u16 tile[64][72];
    const int blk = blockIdx.x;
    const int tid = threadIdx.x;
    if (blk < 1024) {
        const int t0 = (blk & 15) * 64, c0 = ((blk >> 4) & 7) * 64, b = blk >> 7;
        const int f = tid & 15, r0 = tid >> 4;
#pragma unroll
        for (int p = 0; p < 4; ++p) {
            const int c = r0 + p * 16;
            const float4 v = *(const float4*)(x + ((size_t)b * C_ + c0 + c) * T_ + t0 + f * 4);
            tile[c][f * 4 + 0] = f2b(v.x);
            tile[c][f * 4 + 1] = f2b(v.y);
            tile[c][f * 4 + 2] = f2b(v.z);
            tile[c][f * 4 + 3] = f2b(v.w);
        }
        __syncthreads();
#pragma unroll
        for (int p = 0; p < 4; ++p) {
            const int t = r0 + p * 16;
            ushort4 u;
            u.x = tile[f * 4 + 0][t];
            u.y = tile[f * 4 + 1][t];
            u.z = tile[f * 4 + 2][t];
            u.w = tile[f * 4 + 3][t];
            *(ushort4*)(xt + ((size_t)b * T_ + t0 + t) * C_ + c0 + f * 4) = u;
        }
    } else if (blk < 2048) {
        const int gid = (blk - 1024) * 256 + tid;
        const int s = gid >> 16;
        const int off = (gid & 65535) * 4;
        const float* W = (s == 0) ? Wq : (s == 1) ? Wk : (s == 2) ? Wv : Wo;
        const float4 v = *(const float4*)(W + off);
        ushort4 u;
        u.x = f2b(v.x); u.y = f2b(v.y); u.z = f2b(v.z); u.w = f2b(v.w);
        *(ushort4*)(Wh + ((size_t)s << 18) + off) = u;
    } else {
        const int idx = (blk - 2048) * 256 + tid;
        if (idx < 64 * 160) {
            const int d = idx / 160, rel = idx % 160;
            ervt[idx] = (rel < REL_) ? f2b(erv[rel * D_ + d]) : (u16)0;
        } else {
            const int j = idx - 64 * 160;
            if (j < REL_ * D_) erkb[j] = f2b(erk[j]);
        }
    }
}

// ---------------------------------------------------------------------------
// Kernel 1: QKV projection via MFMA (64-tile, 12 blocks/CU TLP).
// ---------------------------------------------------------------------------
__global__ __launch_bounds__(256) void proj_mfma(
    const u16* __restrict__ xt, const u16* __restrict__ Wh,
    const float* __restrict__ bq, const float* __restrict__ bk, const float* __restrict__ bv,
    u16* __restrict__ qh, u16* __restrict__ kh, u16* __restrict__ vt)
{
    __shared__ u16 Wt[64][72];

    const int t0 = blockIdx.x * 64;
    const int h  = blockIdx.y;
    const int sel = blockIdx.z >> 3;
    const int b   = blockIdx.z & 7;
    const int tid = threadIdx.x, wave = tid >> 6, lane = tid & 63;
    const int quad = lane >> 4, l16 = lane & 15;

    const u16* Wbase = Wh + ((size_t)sel << 18) + ((size_t)(h * 64) << 9);
    const u16* A = xt + (((size_t)b * T_ + t0 + wave * 16 + l16) << 9);

    const int so = tid >> 2;
    const int sc = (tid & 3) * 16;
    const u16* wsrc = Wbase + ((size_t)so << 9) + sc;

    f32x4 acc[4] = {{0.f,0.f,0.f,0.f},{0.f,0.f,0.f,0.f},{0.f,0.f,0.f,0.f},{0.f,0.f,0.f,0.f}};

    uint4 wv0 = *(const uint4*)(wsrc);
    uint4 wv1 = *(const uint4*)(wsrc + 8);
#pragma unroll 1
    for (int i = 0; i < 8; ++i) {
        const int c0 = i * 64;
        __syncthreads();
        *(uint4*)&Wt[so][sc] = wv0;
        *(uint4*)&Wt[so][sc + 8] = wv1;
        __syncthreads();
        if (i < 7) {
            wv0 = *(const uint4*)(wsrc + c0 + 64);
            wv1 = *(const uint4*)(wsrc + c0 + 72);
        }
#pragma unroll
        for (int kk = 0; kk < 64; kk += 32) {
            const short8 af = *(const short8*)(A + c0 + kk + quad * 8);
#pragma unroll
            for (int nt = 0; nt < 4; ++nt) {
                const short8 bf = *(const short8*)(&Wt[nt * 16 + l16][kk + quad * 8]);
                acc[nt] = __builtin_amdgcn_mfma_f32_16x16x32_bf16(af, bf, acc[nt], 0, 0, 0);
            }
        }
    }

    const float* bias = (sel == 0) ? bq : (sel == 1) ? bk : bv;
    const int bh = b * 8 + h;
#pragma unroll
    for (int nt = 0; nt < 4; ++nt) {
        const int d = nt * 16 + l16;
        const float bo = bias[h * 64 + d];
#pragma unroll
        for (int rix = 0; rix < 4; ++rix) {
            const int t = t0 + wave * 16 + quad * 4 + rix;
            const u16 val = f2b(acc[nt][rix] + bo);
            if (sel == 2) {
                vt[(((size_t)bh * 64 + d) << 10) + t] = val;
            } else {
                u16* dst = sel ? kh : qh;
                dst[(((size_t)bh * T_ + t) << 6) + d] = val;
            }
        }
    }
}

// ---------------------------------------------------------------------------
// Kernel 2: MFMA attention, 32 q-rows/block, deferred normalization,
// merged QK+PV (per-chunk same-wave produce/consume). Scores stored ONLY in
// a 160-col diagonal band (wrel needs |j-i|<64 band only) + per-wave 32x32
// scratch for out-of-band chunks. Cross-wave O-reduce staged in 2 rounds
// aliased over dead band/scratch. exp in base-2 domain. LDS ~33 KB ->
// 4 blocks/CU (VGPR-capped at 128 by launch_bounds).
// grid = 2048 (XCD-swizzled), block 256.
// ---------------------------------------------------------------------------
__global__ __launch_bounds__(256, 4) void attn_kernel(
    const u16* __restrict__ qh, const u16* __restrict__ kh, const u16* __restrict__ vt,
    const u16* __restrict__ erkb, const u16* __restrict__ ervt,
    const float* __restrict__ xmask, u16* __restrict__ yf)
{
    // pool: Sband [32][168] u16 @0 (10752 B); scratch [4][32][40] u16 @10752
    // (10240 B). ogbuf (16 KB fp32) aliases pool after both are dead.
    __shared__ __align__(16) char pool[10752 + 10240];
    __shared__ u16   sw[32][168];      // phase A: srel*log2e; phase B: wrel (raw)
    __shared__ float red[4][32][2];    // per-wave {sum, phi}
    __shared__ float invrow[32];

    u16 (*Sband)[168]   = (u16 (*)[168])pool;
    u16 (*scr)[32][40]  = (u16 (*)[32][40])(pool + 10752);

    const int gid = blockIdx.x;
    const int x8 = gid & 7, r5 = gid >> 3;
    const int bh = x8 + 8 * (r5 >> 5);
    const int i0 = (r5 & 31) * 32;
    const int b = bh >> 3, h = bh & 7;
    const int tid = threadIdx.x, wave = tid >> 6, lane = tid & 63;
    const int quad = lane >> 4, l16 = lane & 15;

    // Q A-frags for both 16-row groups
    short8 qa[2][2];
#pragma unroll
    for (int g = 0; g < 2; ++g) {
        const u16* qrow = qh + (((size_t)bh * T_ + i0 + g * 16 + l16) << 6);
        qa[g][0] = *(const short8*)(qrow + quad * 8);
        qa[g][1] = *(const short8*)(qrow + 32 + quad * 8);
    }

    // ---- phase 1: srel via MFMA (scaled by log2(e) for exp2 domain) ----
    for (int tile = wave; tile < 9; tile += 4) {
        const int rel = tile * 16 + l16;
        const int rl = rel > 128 ? 128 : rel;
        const u16* ep = erkb + rl * 64 + quad * 8;
        const short8 b0 = *(const short8*)(ep);
        const short8 b1 = *(const short8*)(ep + 32);
#pragma unroll
        for (int g = 0; g < 2; ++g) {
            f32x4 m = {0.f, 0.f, 0.f, 0.f};
            m = __builtin_amdgcn_mfma_f32_16x16x32_bf16(qa[g][0], b0, m, 0, 0, 0);
            m = __builtin_amdgcn_mfma_f32_16x16x32_bf16(qa[g][1], b1, m, 0, 0, 0);
            if (rel < 129) {
#pragma unroll
                for (int rix = 0; rix < 4; ++rix)
                    sw[g * 16 + quad * 4 + rix][rel] = f2b(m[rix] * 1.4426950408889634f);
            }
        }
    }
    __syncthreads();                                    // barrier 1

    float slo_c[2][4], shi_c[2][4];
#pragma unroll
    for (int g = 0; g < 2; ++g)
#pragma unroll
        for (int rix = 0; rix < 4; ++rix) {
            const int row = g * 16 + quad * 4 + rix;
            slo_c[g][rix] = b2f(sw[row][0]);
            shi_c[g][rix] = b2f(sw[row][2 * K_]);
        }

    // ---- merged QK + exp2 + partial-PV over this wave's j-quarter ----
    float psum[2][4] = {{0.f,0.f,0.f,0.f},{0.f,0.f,0.f,0.f}};
    float phi [2][4] = {{0.f,0.f,0.f,0.f},{0.f,0.f,0.f,0.f}};
    f32x4 og[4][2];
#pragma unroll
    for (int s = 0; s < 4; ++s)
#pragma unroll
        for (int g = 0; g < 2; ++g) og[s][g] = (f32x4){0.f, 0.f, 0.f, 0.f};

    {
        const u16* kb = kh + ((size_t)bh << 16);
        const u16* vbase = vt + ((size_t)bh << 16);
        const int bandlo = i0 - 64, bandhi = i0 + 96;   // chunk-aligned band
#pragma unroll 1
        for (int c = 0; c < 8; ++c) {
            const int jc = wave * 256 + c * 32;
            const bool inband = (jc >= bandlo) && (jc < bandhi);
#pragma unroll
            for (int half = 0; half < 2; ++half) {
                const int j0 = jc + half * 16;
                const u16* krow = kb + ((size_t)(j0 + l16) << 6);
                const short8 kb0 = *(const short8*)(krow + quad * 8);
                const short8 kb1 = *(const short8*)(krow + 32 + quad * 8);
                const int j = j0 + l16;
                const float xmv = xmask[b * T_ + j];
#pragma unroll
                for (int g = 0; g < 2; ++g) {
                    f32x4 acc = {0.f, 0.f, 0.f, 0.f};
                    acc = __builtin_amdgcn_mfma_f32_16x16x32_bf16(qa[g][0], kb0, acc, 0, 0, 0);
                    acc = __builtin_amdgcn_mfma_f32_16x16x32_bf16(qa[g][1], kb1, acc, 0, 0, 0);
                    const int dd = j0 - (i0 + g * 16);
#pragma unroll
                    for (int rix = 0; rix < 4; ++rix) {
                        const int row = g * 16 + quad * 4 + rix;
                        const int i = i0 + row;
                        float sr;
                        if (dd <= -79) sr = slo_c[g][rix];
                        else if (dd >= 79) sr = shi_c[g][rix];
                        else {
                            int rel = j - i;
                            rel = (rel < -K_) ? -K_ : (rel > K_) ? K_ : rel;
                            sr = b2f(sw[row][rel + K_]);
                        }
                        float val = acc[rix] * 0.18033688011112042f + sr;  // 0.125*log2e
                        val = (xmv > 0.f) ? val : -1e9f;
                        const u16 pb = f2b(exp2f(val));
                        const float er = b2f(pb);
                        if (inband) Sband[row][j - i0 + 64] = pb;
                        else        scr[wave][row][half * 16 + l16] = pb;
                        psum[g][rix] += er;
                        if (dd >= 79)      phi[g][rix] += er;
                        else if (dd > -79) phi[g][rix] += (j >= i + K_) ? er : 0.f;
                    }
                }
            }
            // partial PV for this 32-column chunk (same-wave data, no barrier)
            const u16* pr0 = inband ? &Sband[l16][jc - i0 + 64]      : &scr[wave][l16][0];
            const u16* pr1 = inband ? &Sband[16 + l16][jc - i0 + 64] : &scr[wave][16 + l16][0];
            const short8 pb0 = *(const short8*)(pr0 + quad * 8);
            const short8 pb1 = *(const short8*)(pr1 + quad * 8);
#pragma unroll
            for (int s = 0; s < 4; ++s) {
                const short8 af = *(const short8*)(vbase + ((size_t)(s * 16 + l16) << 10) + jc + quad * 8);
                og[s][0] = __builtin_amdgcn_mfma_f32_16x16x32_bf16(af, pb0, og[s][0], 0, 0, 0);
                og[s][1] = __builtin_amdgcn_mfma_f32_16x16x32_bf16(af, pb1, og[s][1], 0, 0, 0);
            }
        }
#pragma unroll
        for (int m = 1; m < 16; m <<= 1)
#pragma unroll
            for (int g = 0; g < 2; ++g)
#pragma unroll
                for (int rix = 0; rix < 4; ++rix) {
                    psum[g][rix] += __shfl_xor(psum[g][rix], m);
                    phi[g][rix]  += __shfl_xor(phi[g][rix], m);
                }
        if (l16 == 0)
#pragma unroll
            for (int g = 0; g < 2; ++g)
#pragma unroll
                for (int rix = 0; rix < 4; ++rix) {
                    const int row = g * 16 + quad * 4 + rix;
                    red[wave][row][0] = psum[g][rix];
                    red[wave][row][1] = phi[g][rix];
                }
    }
    __syncthreads();                                    // barrier 2

    // ---- wrel (raw) from Sband; slo by complement; invrow ----
    {
        const int rr = tid >> 3;        // 0..31
        const int c0 = tid & 7;
        const float sumrow = red[0][rr][0] + red[1][rr][0] + red[2][rr][0] + red[3][rr][0];
        const float phirow = red[0][rr][1] + red[1][rr][1] + red[2][rr][1] + red[3][rr][1];
        float intsum = 0.f;
        for (int rel = c0; rel < 168; rel += 8) {
            if (rel == 0 || rel == 2 * K_) continue;
            u16 v = 0;
            if (rel < 2 * K_) {
                const int j = i0 + rr + rel - K_;
                if (j >= 0 && j < T_) v = Sband[rr][rr + rel];   // jb = rr+rel
                intsum += b2f(v);
            }
            sw[rr][rel] = v;
        }
        intsum += __shfl_xor(intsum, 1);
        intsum += __shfl_xor(intsum, 2);
        intsum += __shfl_xor(intsum, 4);
        if (c0 == 0) {
            sw[rr][2 * K_] = f2b(phirow);
            sw[rr][0]      = f2b(sumrow - intsum - phirow);
            invrow[rr]     = 1.0f / sumrow;
        }
    }
    __syncthreads();                                    // barrier 3 (Sband dead)

    // ---- cross-wave O reduction, 2 rounds of 16 KB aliased over pool ----
    float* ogbuf = (float*)pool;
    f32x4 accg[2];
#pragma unroll 1
    for (int r = 0; r < 2; ++r) {
        if (r) __syncthreads();                         // barrier 5: round-0 reads done
#pragma unroll
        for (int sl = 0; sl < 2; ++sl)
#pragma unroll
            for (int g = 0; g < 2; ++g)
                *(f32x4*)&ogbuf[((wave * 4 + sl * 2 + g) * 64 + lane) * 4] = og[2 * r + sl][g];
        __syncthreads();                                // barrier 4 / 6
        if ((wave >> 1) == r) {
            const int sl = wave & 1;
#pragma unroll
            for (int g = 0; g < 2; ++g) {
                const int base = ((sl * 2 + g) * 64 + lane) * 4;
                const f32x4 a0 = *(const f32x4*)&ogbuf[base];
                const f32x4 a1 = *(const f32x4*)&ogbuf[1024 + base];
                const f32x4 a2 = *(const f32x4*)&ogbuf[2048 + base];
                const f32x4 a3 = *(const f32x4*)&ogbuf[3072 + base];
#pragma unroll
                for (int rix = 0; rix < 4; ++rix)
                    accg[g][rix] = (a0[rix] + a1[rix]) + (a2[rix] + a3[rix]);
            }
        }
    }

    // ---- rel-v MFMA + normalize + store yf (B,T,C) bf16 ----
    {
        const int dh = wave * 16 + l16;
        const u16* ep = ervt + dh * 160;
#pragma unroll
        for (int kt = 0; kt < 5; ++kt) {
            const short8 af = *(const short8*)(ep + kt * 32 + quad * 8);
            const short8 p0 = *(const short8*)(&sw[l16][kt * 32 + quad * 8]);
            const short8 p1 = *(const short8*)(&sw[16 + l16][kt * 32 + quad * 8]);
            accg[0] = __builtin_amdgcn_mfma_f32_16x16x32_bf16(af, p0, accg[0], 0, 0, 0);
            accg[1] = __builtin_amdgcn_mfma_f32_16x16x32_bf16(af, p1, accg[1], 0, 0, 0);
        }
        const int dbase = (h << 6) + wave * 16 + quad * 4;
#pragma unroll
        for (int g = 0; g < 2; ++g) {
            const float iv = invrow[g * 16 + l16];
            ushort4 u;
            u.x = f2b(accg[g][0] * iv); u.y = f2b(accg[g][1] * iv);
            u.z = f2b(accg[g][2] * iv); u.w = f2b(accg[g][3] * iv);
            *(ushort4*)(yf + (((size_t)b * T_ + i0 + g * 16 + l16) << 9) + dbase) = u;
        }
    }
}

// ---------------------------------------------------------------------------
// Kernel 3: output projection via MFMA (64-tile). yf tile staged in LDS.
// ---------------------------------------------------------------------------
__global__ __launch_bounds__(256) void outproj_mfma(
    const u16* __restrict__ yf, const u16* __restrict__ Woh, const float* __restrict__ bo,
    const float* __restrict__ xmask, float* __restrict__ out)
{
    __shared__ u16 Yt[64][72];

    const int o0 = blockIdx.x * 64;
    const int b  = blockIdx.y >> 4;
    const int t0 = (blockIdx.y & 15) * 64;
    const int tid = threadIdx.x, wave = tid >> 6, lane = tid & 63;
    const int quad = lane >> 4, l16 = lane & 15;

    const u16* A = Woh + ((size_t)(o0 + wave * 16 + l16) << 9);

    const int so = tid >> 2;
    const int sc = (tid & 3) * 16;
    const u16* ysrc = yf + (((size_t)b * T_ + t0 + so) << 9) + sc;

    f32x4 acc[4] = {{0.f,0.f,0.f,0.f},{0.f,0.f,0.f,0.f},{0.f,0.f,0.f,0.f},{0.f,0.f,0.f,0.f}};

    uint4 wv0 = *(const uint4*)(ysrc);
    uint4 wv1 = *(const uint4*)(ysrc + 8);
#pragma unroll 1
    for (int i = 0; i < 8; ++i) {
        const int c0 = i * 64;
        __syncthreads();
        *(uint4*)&Yt[so][sc] = wv0;
        *(uint4*)&Yt[so][sc + 8] = wv1;
        __syncthreads();
        if (i < 7) {
            wv0 = *(const uint4*)(ysrc + c0 + 64);
            wv1 = *(const uint4*)(ysrc + c0 + 72);
        }
#pragma unroll
        for (int kk = 0; kk < 64; kk += 32) {
            const short8 af = *(const short8*)(A + c0 + kk + quad * 8);
#pragma unroll
            for (int nt = 0; nt < 4; ++nt) {
                const short8 bf = *(const short8*)(&Yt[nt * 16 + l16][kk + quad * 8]);
                acc[nt] = __builtin_amdgcn_mfma_f32_16x16x32_bf16(af, bf, acc[nt], 0, 0, 0);
            }
        }
    }

#pragma unroll
    for (int nt = 0; nt < 4; ++nt) {
        const int t = t0 + nt * 16 + l16;
        const float xmv = xmask[b * T_ + t];
#pragma unroll
        for (int rix = 0; rix < 4; ++rix) {
            const int o = o0 + wave * 16 + quad * 4 + rix;
            out[((size_t)b * C_ + o) * T_ + t] = (acc[nt][rix] + bo[o]) * xmv;
        }
    }
}

// ---------------------------------------------------------------------------
extern "C" void kernel_launch(void* const* d_in, const int* in_sizes, int n_in,
                              void* d_out, int out_size, void* d_ws, size_t ws_size,
                              hipStream_t stream) {
    const float* x     = (const float*)d_in[0];
    const float* xmask = (const float*)d_in[1];
    const float* Wq    = (const float*)d_in[2];
    const float* bq    = (const float*)d_in[3];
    const float* Wk    = (const float*)d_in[4];
    const float* bk    = (const float*)d_in[5];
    const float* Wv    = (const float*)d_in[6];
    const float* bv    = (const float*)d_in[7];
    const float* Wo    = (const float*)d_in[8];
    const float* bo    = (const float*)d_in[9];
    const float* erk   = (const float*)d_in[10];
    const float* erv   = (const float*)d_in[11];

    // workspace (bf16): xt@0 (8MB), Wh@8M (2MB), qh@10M, kh@18M, vt@26M,
    // yf@34M (8MB each), ervt@44040192 (20480B), erkb@44060672 (16512B)
    const size_t need = 44077184;
    if (ws_size < need) return;
    u16* xt   = (u16*)d_ws;
    u16* Wh   = (u16*)((char*)d_ws + 8388608);
    u16* qh   = (u16*)((char*)d_ws + 10485760);
    u16* kh   = (u16*)((char*)d_ws + 18874368);
    u16* vt   = (u16*)((char*)d_ws + 27262976);
    u16* yf   = (u16*)((char*)d_ws + 35651584);
    u16* ervt = (u16*)((char*)d_ws + 44040192);
    u16* erkb = (u16*)((char*)d_ws + 44060672);
    float* out = (float*)d_out;

    cast_all_kernel<<<dim3(2121), 256, 0, stream>>>(
        x, Wq, Wk, Wv, Wo, erk, erv, xt, Wh, ervt, erkb);
    proj_mfma<<<dim3(T_ / 64, H_, 3 * B_), 256, 0, stream>>>(
        xt, Wh, bq, bk, bv, qh, kh, vt);
    attn_kernel<<<dim3(2048), 256, 0, stream>>>(
        qh, kh, vt, erkb, ervt, xmask, yf);
    outproj_mfma<<<dim3(C_ / 64, B_ * (T_ / 64)), 256, 0, stream>>>(
        yf, Wh + ((size_t)3 << 18), bo, xmask, out);
}

// Round 12
// 258.621 us; speedup vs baseline: 1.0885x; 1.0885x over previous
//
#include <hip/hip_runtime.h>

// (B,C,T)=(8,512,1024), H=8, D=64, K=64, REL=129. I/O fp32; internal bf16.
#define B_   8
#define C_   512
#define T_   1024
#define H_   8
#define D_   64
#define K_   64
#define REL_ 129

typedef unsigned short u16;
typedef __attribute__((ext_vector_type(8))) short short8;   // 8 bf16 (4 VGPRs)
typedef __attribute__((ext_vector_type(4))) float f32x4;

__device__ __forceinline__ float b2f(u16 u) {
    return __uint_as_float(((unsigned)u) << 16);
}
__device__ __forceinline__ u16 f2b(float f) {
    unsigned x = __float_as_uint(f);
    x += 0x7fffu + ((x >> 16) & 1u);   // RNE
    return (u16)(x >> 16);
}

// ---------------------------------------------------------------------------
// Kernel 0: all input casts in one launch.
// ---------------------------------------------------------------------------
__global__ __launch_bounds__(256) void cast_all_kernel(
    const float* __restrict__ x,
    const float* __restrict__ Wq, const float* __restrict__ Wk,
    const float* __restrict__ Wv, const float* __restrict__ Wo,
    const float* __restrict__ erk, const float* __restrict__ erv,
    u16* __restrict__ xt, u16* __restrict__ Wh,
    u16* __restrict__ ervt, u16* __restrict__ erkb)
{
    __shared__ u16 tile[64][72];
    const int blk = blockIdx.x;
    const int tid = threadIdx.x;
    if (blk < 1024) {
        const int t0 = (blk & 15) * 64, c0 = ((blk >> 4) & 7) * 64, b = blk >> 7;
        const int f = tid & 15, r0 = tid >> 4;
#pragma unroll
        for (int p = 0; p < 4; ++p) {
            const int c = r0 + p * 16;
            const float4 v = *(const float4*)(x + ((size_t)b * C_ + c0 + c) * T_ + t0 + f * 4);
            tile[c][f * 4 + 0] = f2b(v.x);
            tile[c][f * 4 + 1] = f2b(v.y);
            tile[c][f * 4 + 2] = f2b(v.z);
            tile[c][f * 4 + 3] = f2b(v.w);
        }
        __syncthreads();
#pragma unroll
        for (int p = 0; p < 4; ++p) {
            const int t = r0 + p * 16;
            ushort4 u;
            u.x = tile[f * 4 + 0][t];
            u.y = tile[f * 4 + 1][t];
            u.z = tile[f * 4 + 2][t];
            u.w = tile[f * 4 + 3][t];
            *(ushort4*)(xt + ((size_t)b * T_ + t0 + t) * C_ + c0 + f * 4) = u;
        }
    } else if (blk < 2048) {
        const int gid = (blk - 1024) * 256 + tid;
        const int s = gid >> 16;
        const int off = (gid & 65535) * 4;
        const float* W = (s == 0) ? Wq : (s == 1) ? Wk : (s == 2) ? Wv : Wo;
        const float4 v = *(const float4*)(W + off);
        ushort4 u;
        u.x = f2b(v.x); u.y = f2b(v.y); u.z = f2b(v.z); u.w = f2b(v.w);
        *(ushort4*)(Wh + ((size_t)s << 18) + off) = u;
    } else {
        const int idx = (blk - 2048) * 256 + tid;
        if (idx < 64 * 160) {
            const int d = idx / 160, rel = idx % 160;
            ervt[idx] = (rel < REL_) ? f2b(erv[rel * D_ + d]) : (u16)0;
        } else {
            const int j = idx - 64 * 160;
            if (j < REL_ * D_) erkb[j] = f2b(erk[j]);
        }
    }
}

// ---------------------------------------------------------------------------
// Kernel 1: QKV projection via MFMA (64-tile, 12 blocks/CU TLP).
// ---------------------------------------------------------------------------
__global__ __launch_bounds__(256) void proj_mfma(
    const u16* __restrict__ xt, const u16* __restrict__ Wh,
    const float* __restrict__ bq, const float* __restrict__ bk, const float* __restrict__ bv,
    u16* __restrict__ qh, u16* __restrict__ kh, u16* __restrict__ vt)
{
    __shared__ u16 Wt[64][72];

    const int t0 = blockIdx.x * 64;
    const int h  = blockIdx.y;
    const int sel = blockIdx.z >> 3;
    const int b   = blockIdx.z & 7;
    const int tid = threadIdx.x, wave = tid >> 6, lane = tid & 63;
    const int quad = lane >> 4, l16 = lane & 15;

    const u16* Wbase = Wh + ((size_t)sel << 18) + ((size_t)(h * 64) << 9);
    const u16* A = xt + (((size_t)b * T_ + t0 + wave * 16 + l16) << 9);

    const int so = tid >> 2;
    const int sc = (tid & 3) * 16;
    const u16* wsrc = Wbase + ((size_t)so << 9) + sc;

    f32x4 acc[4] = {{0.f,0.f,0.f,0.f},{0.f,0.f,0.f,0.f},{0.f,0.f,0.f,0.f},{0.f,0.f,0.f,0.f}};

    uint4 wv0 = *(const uint4*)(wsrc);
    uint4 wv1 = *(const uint4*)(wsrc + 8);
#pragma unroll 1
    for (int i = 0; i < 8; ++i) {
        const int c0 = i * 64;
        __syncthreads();
        *(uint4*)&Wt[so][sc] = wv0;
        *(uint4*)&Wt[so][sc + 8] = wv1;
        __syncthreads();
        if (i < 7) {
            wv0 = *(const uint4*)(wsrc + c0 + 64);
            wv1 = *(const uint4*)(wsrc + c0 + 72);
        }
#pragma unroll
        for (int kk = 0; kk < 64; kk += 32) {
            const short8 af = *(const short8*)(A + c0 + kk + quad * 8);
#pragma unroll
            for (int nt = 0; nt < 4; ++nt) {
                const short8 bf = *(const short8*)(&Wt[nt * 16 + l16][kk + quad * 8]);
                acc[nt] = __builtin_amdgcn_mfma_f32_16x16x32_bf16(af, bf, acc[nt], 0, 0, 0);
            }
        }
    }

    const float* bias = (sel == 0) ? bq : (sel == 1) ? bk : bv;
    const int bh = b * 8 + h;
#pragma unroll
    for (int nt = 0; nt < 4; ++nt) {
        const int d = nt * 16 + l16;
        const float bo = bias[h * 64 + d];
#pragma unroll
        for (int rix = 0; rix < 4; ++rix) {
            const int t = t0 + wave * 16 + quad * 4 + rix;
            const u16 val = f2b(acc[nt][rix] + bo);
            if (sel == 2) {
                vt[(((size_t)bh * 64 + d) << 10) + t] = val;
            } else {
                u16* dst = sel ? kh : qh;
                dst[(((size_t)bh * T_ + t) << 6) + d] = val;
            }
        }
    }
}

// ---------------------------------------------------------------------------
// Kernel 2: MFMA attention, 32 q-rows/block, deferred normalization,
// merged QK+PV, 160-col diagonal band score buffer + per-wave scratch,
// 2-round cross-wave O reduction aliased over dead band. exp2 domain.
// LDS ~33 KB. launch_bounds(256,2): VGPR cap 256 — compiler allocates
// naturally (~90-110); if <=128 HW schedules 4 blocks/CU. (256,4) in R11
// forced VGPR=64 and catastrophic scratch spill — do not reinstate.
// grid = 2048 (XCD-swizzled), block 256.
// ---------------------------------------------------------------------------
__global__ __launch_bounds__(256, 2) void attn_kernel(
    const u16* __restrict__ qh, const u16* __restrict__ kh, const u16* __restrict__ vt,
    const u16* __restrict__ erkb, const u16* __restrict__ ervt,
    const float* __restrict__ xmask, u16* __restrict__ yf)
{
    // pool: Sband [32][168] u16 @0 (10752 B); scratch [4][32][40] u16 @10752
    // (10240 B). ogbuf (16 KB fp32) aliases pool after both are dead.
    __shared__ __align__(16) char pool[10752 + 10240];
    __shared__ u16   sw[32][168];      // phase A: srel*log2e; phase B: wrel (raw)
    __shared__ float red[4][32][2];    // per-wave {sum, phi}
    __shared__ float invrow[32];

    u16 (*Sband)[168]   = (u16 (*)[168])pool;
    u16 (*scr)[32][40]  = (u16 (*)[32][40])(pool + 10752);

    const int gid = blockIdx.x;
    const int x8 = gid & 7, r5 = gid >> 3;
    const int bh = x8 + 8 * (r5 >> 5);
    const int i0 = (r5 & 31) * 32;
    const int b = bh >> 3, h = bh & 7;
    const int tid = threadIdx.x, wave = tid >> 6, lane = tid & 63;
    const int quad = lane >> 4, l16 = lane & 15;

    // Q A-frags for both 16-row groups
    short8 qa[2][2];
#pragma unroll
    for (int g = 0; g < 2; ++g) {
        const u16* qrow = qh + (((size_t)bh * T_ + i0 + g * 16 + l16) << 6);
        qa[g][0] = *(const short8*)(qrow + quad * 8);
        qa[g][1] = *(const short8*)(qrow + 32 + quad * 8);
    }

    // ---- phase 1: srel via MFMA (scaled by log2(e) for exp2 domain) ----
    for (int tile = wave; tile < 9; tile += 4) {
        const int rel = tile * 16 + l16;
        const int rl = rel > 128 ? 128 : rel;
        const u16* ep = erkb + rl * 64 + quad * 8;
        const short8 b0 = *(const short8*)(ep);
        const short8 b1 = *(const short8*)(ep + 32);
#pragma unroll
        for (int g = 0; g < 2; ++g) {
            f32x4 m = {0.f, 0.f, 0.f, 0.f};
            m = __builtin_amdgcn_mfma_f32_16x16x32_bf16(qa[g][0], b0, m, 0, 0, 0);
            m = __builtin_amdgcn_mfma_f32_16x16x32_bf16(qa[g][1], b1, m, 0, 0, 0);
            if (rel < 129) {
#pragma unroll
                for (int rix = 0; rix < 4; ++rix)
                    sw[g * 16 + quad * 4 + rix][rel] = f2b(m[rix] * 1.4426950408889634f);
            }
        }
    }
    __syncthreads();                                    // barrier 1

    float slo_c[2][4], shi_c[2][4];
#pragma unroll
    for (int g = 0; g < 2; ++g)
#pragma unroll
        for (int rix = 0; rix < 4; ++rix) {
            const int row = g * 16 + quad * 4 + rix;
            slo_c[g][rix] = b2f(sw[row][0]);
            shi_c[g][rix] = b2f(sw[row][2 * K_]);
        }

    // ---- merged QK + exp2 + partial-PV over this wave's j-quarter ----
    float psum[2][4] = {{0.f,0.f,0.f,0.f},{0.f,0.f,0.f,0.f}};
    float phi [2][4] = {{0.f,0.f,0.f,0.f},{0.f,0.f,0.f,0.f}};
    f32x4 og[4][2];
#pragma unroll
    for (int s = 0; s < 4; ++s)
#pragma unroll
        for (int g = 0; g < 2; ++g) og[s][g] = (f32x4){0.f, 0.f, 0.f, 0.f};

    {
        const u16* kb = kh + ((size_t)bh << 16);
        const u16* vbase = vt + ((size_t)bh << 16);
        const int bandlo = i0 - 64, bandhi = i0 + 96;   // chunk-aligned band
#pragma unroll 1
        for (int c = 0; c < 8; ++c) {
            const int jc = wave * 256 + c * 32;
            const bool inband = (jc >= bandlo) && (jc < bandhi);
#pragma unroll
            for (int half = 0; half < 2; ++half) {
                const int j0 = jc + half * 16;
                const u16* krow = kb + ((size_t)(j0 + l16) << 6);
                const short8 kb0 = *(const short8*)(krow + quad * 8);
                const short8 kb1 = *(const short8*)(krow + 32 + quad * 8);
                const int j = j0 + l16;
                const float xmv = xmask[b * T_ + j];
#pragma unroll
                for (int g = 0; g < 2; ++g) {
                    f32x4 acc = {0.f, 0.f, 0.f, 0.f};
                    acc = __builtin_amdgcn_mfma_f32_16x16x32_bf16(qa[g][0], kb0, acc, 0, 0, 0);
                    acc = __builtin_amdgcn_mfma_f32_16x16x32_bf16(qa[g][1], kb1, acc, 0, 0, 0);
                    const int dd = j0 - (i0 + g * 16);
#pragma unroll
                    for (int rix = 0; rix < 4; ++rix) {
                        const int row = g * 16 + quad * 4 + rix;
                        const int i = i0 + row;
                        float sr;
                        if (dd <= -79) sr = slo_c[g][rix];
                        else if (dd >= 79) sr = shi_c[g][rix];
                        else {
                            int rel = j - i;
                            rel = (rel < -K_) ? -K_ : (rel > K_) ? K_ : rel;
                            sr = b2f(sw[row][rel + K_]);
                        }
                        float val = acc[rix] * 0.18033688011112042f + sr;  // 0.125*log2e
                        val = (xmv > 0.f) ? val : -1e9f;
                        const u16 pb = f2b(exp2f(val));
                        const float er = b2f(pb);
                        if (inband) Sband[row][j - i0 + 64] = pb;
                        else        scr[wave][row][half * 16 + l16] = pb;
                        psum[g][rix] += er;
                        if (dd >= 79)      phi[g][rix] += er;
                        else if (dd > -79) phi[g][rix] += (j >= i + K_) ? er : 0.f;
                    }
                }
            }
            // partial PV for this 32-column chunk (same-wave data, no barrier)
            const u16* pr0 = inband ? &Sband[l16][jc - i0 + 64]      : &scr[wave][l16][0];
            const u16* pr1 = inband ? &Sband[16 + l16][jc - i0 + 64] : &scr[wave][16 + l16][0];
            const short8 pb0 = *(const short8*)(pr0 + quad * 8);
            const short8 pb1 = *(const short8*)(pr1 + quad * 8);
#pragma unroll
            for (int s = 0; s < 4; ++s) {
                const short8 af = *(const short8*)(vbase + ((size_t)(s * 16 + l16) << 10) + jc + quad * 8);
                og[s][0] = __builtin_amdgcn_mfma_f32_16x16x32_bf16(af, pb0, og[s][0], 0, 0, 0);
                og[s][1] = __builtin_amdgcn_mfma_f32_16x16x32_bf16(af, pb1, og[s][1], 0, 0, 0);
            }
        }
#pragma unroll
        for (int m = 1; m < 16; m <<= 1)
#pragma unroll
            for (int g = 0; g < 2; ++g)
#pragma unroll
                for (int rix = 0; rix < 4; ++rix) {
                    psum[g][rix] += __shfl_xor(psum[g][rix], m);
                    phi[g][rix]  += __shfl_xor(phi[g][rix], m);
                }
        if (l16 == 0)
#pragma unroll
            for (int g = 0; g < 2; ++g)
#pragma unroll
                for (int rix = 0; rix < 4; ++rix) {
                    const int row = g * 16 + quad * 4 + rix;
                    red[wave][row][0] = psum[g][rix];
                    red[wave][row][1] = phi[g][rix];
                }
    }
    __syncthreads();                                    // barrier 2

    // ---- wrel (raw) from Sband; slo by complement; invrow ----
    {
        const int rr = tid >> 3;        // 0..31
        const int c0 = tid & 7;
        const float sumrow = red[0][rr][0] + red[1][rr][0] + red[2][rr][0] + red[3][rr][0];
        const float phirow = red[0][rr][1] + red[1][rr][1] + red[2][rr][1] + red[3][rr][1];
        float intsum = 0.f;
        for (int rel = c0; rel < 168; rel += 8) {
            if (rel == 0 || rel == 2 * K_) continue;
            u16 v = 0;
            if (rel < 2 * K_) {
                const int j = i0 + rr + rel - K_;
                if (j >= 0 && j < T_) v = Sband[rr][rr + rel];   // jb = rr+rel
                intsum += b2f(v);
            }
            sw[rr][rel] = v;
        }
        intsum += __shfl_xor(intsum, 1);
        intsum += __shfl_xor(intsum, 2);
        intsum += __shfl_xor(intsum, 4);
        if (c0 == 0) {
            sw[rr][2 * K_] = f2b(phirow);
            sw[rr][0]      = f2b(sumrow - intsum - phirow);
            invrow[rr]     = 1.0f / sumrow;
        }
    }
    __syncthreads();                                    // barrier 3 (Sband dead)

    // ---- cross-wave O reduction, 2 rounds of 16 KB aliased over pool ----
    float* ogbuf = (float*)pool;
    f32x4 accg[2];
#pragma unroll 1
    for (int r = 0; r < 2; ++r) {
        if (r) __syncthreads();                         // round-0 reads done
#pragma unroll
        for (int sl = 0; sl < 2; ++sl)
#pragma unroll
            for (int g = 0; g < 2; ++g)
                *(f32x4*)&ogbuf[((wave * 4 + sl * 2 + g) * 64 + lane) * 4] = og[2 * r + sl][g];
        __syncthreads();
        if ((wave >> 1) == r) {
            const int sl = wave & 1;
#pragma unroll
            for (int g = 0; g < 2; ++g) {
                const int base = ((sl * 2 + g) * 64 + lane) * 4;
                const f32x4 a0 = *(const f32x4*)&ogbuf[base];
                const f32x4 a1 = *(const f32x4*)&ogbuf[1024 + base];
                const f32x4 a2 = *(const f32x4*)&ogbuf[2048 + base];
                const f32x4 a3 = *(const f32x4*)&ogbuf[3072 + base];
#pragma unroll
                for (int rix = 0; rix < 4; ++rix)
                    accg[g][rix] = (a0[rix] + a1[rix]) + (a2[rix] + a3[rix]);
            }
        }
    }

    // ---- rel-v MFMA + normalize + store yf (B,T,C) bf16 ----
    {
        const int dh = wave * 16 + l16;
        const u16* ep = ervt + dh * 160;
#pragma unroll
        for (int kt = 0; kt < 5; ++kt) {
            const short8 af = *(const short8*)(ep + kt * 32 + quad * 8);
            const short8 p0 = *(const short8*)(&sw[l16][kt * 32 + quad * 8]);
            const short8 p1 = *(const short8*)(&sw[16 + l16][kt * 32 + quad * 8]);
            accg[0] = __builtin_amdgcn_mfma_f32_16x16x32_bf16(af, p0, accg[0], 0, 0, 0);
            accg[1] = __builtin_amdgcn_mfma_f32_16x16x32_bf16(af, p1, accg[1], 0, 0, 0);
        }
        const int dbase = (h << 6) + wave * 16 + quad * 4;
#pragma unroll
        for (int g = 0; g < 2; ++g) {
            const float iv = invrow[g * 16 + l16];
            ushort4 u;
            u.x = f2b(accg[g][0] * iv); u.y = f2b(accg[g][1] * iv);
            u.z = f2b(accg[g][2] * iv); u.w = f2b(accg[g][3] * iv);
            *(ushort4*)(yf + (((size_t)b * T_ + i0 + g * 16 + l16) << 9) + dbase) = u;
        }
    }
}

// ---------------------------------------------------------------------------
// Kernel 3: output projection via MFMA (64-tile). yf tile staged in LDS.
// ---------------------------------------------------------------------------
__global__ __launch_bounds__(256) void outproj_mfma(
    const u16* __restrict__ yf, const u16* __restrict__ Woh, const float* __restrict__ bo,
    const float* __restrict__ xmask, float* __restrict__ out)
{
    __shared__ u16 Yt[64][72];

    const int o0 = blockIdx.x * 64;
    const int b  = blockIdx.y >> 4;
    const int t0 = (blockIdx.y & 15) * 64;
    const int tid = threadIdx.x, wave = tid >> 6, lane = tid & 63;
    const int quad = lane >> 4, l16 = lane & 15;

    const u16* A = Woh + ((size_t)(o0 + wave * 16 + l16) << 9);

    const int so = tid >> 2;
    const int sc = (tid & 3) * 16;
    const u16* ysrc = yf + (((size_t)b * T_ + t0 + so) << 9) + sc;

    f32x4 acc[4] = {{0.f,0.f,0.f,0.f},{0.f,0.f,0.f,0.f},{0.f,0.f,0.f,0.f},{0.f,0.f,0.f,0.f}};

    uint4 wv0 = *(const uint4*)(ysrc);
    uint4 wv1 = *(const uint4*)(ysrc + 8);
#pragma unroll 1
    for (int i = 0; i < 8; ++i) {
        const int c0 = i * 64;
        __syncthreads();
        *(uint4*)&Yt[so][sc] = wv0;
        *(uint4*)&Yt[so][sc + 8] = wv1;
        __syncthreads();
        if (i < 7) {
            wv0 = *(const uint4*)(ysrc + c0 + 64);
            wv1 = *(const uint4*)(ysrc + c0 + 72);
        }
#pragma unroll
        for (int kk = 0; kk < 64; kk += 32) {
            const short8 af = *(const short8*)(A + c0 + kk + quad * 8);
#pragma unroll
            for (int nt = 0; nt < 4; ++nt) {
                const short8 bf = *(const short8*)(&Yt[nt * 16 + l16][kk + quad * 8]);
                acc[nt] = __builtin_amdgcn_mfma_f32_16x16x32_bf16(af, bf, acc[nt], 0, 0, 0);
            }
        }
    }

#pragma unroll
    for (int nt = 0; nt < 4; ++nt) {
        const int t = t0 + nt * 16 + l16;
        const float xmv = xmask[b * T_ + t];
#pragma unroll
        for (int rix = 0; rix < 4; ++rix) {
            const int o = o0 + wave * 16 + quad * 4 + rix;
            out[((size_t)b * C_ + o) * T_ + t] = (acc[nt][rix] + bo[o]) * xmv;
        }
    }
}

// ---------------------------------------------------------------------------
extern "C" void kernel_launch(void* const* d_in, const int* in_sizes, int n_in,
                              void* d_out, int out_size, void* d_ws, size_t ws_size,
                              hipStream_t stream) {
    const float* x     = (const float*)d_in[0];
    const float* xmask = (const float*)d_in[1];
    const float* Wq    = (const float*)d_in[2];
    const float* bq    = (const float*)d_in[3];
    const float* Wk    = (const float*)d_in[4];
    const float* bk    = (const float*)d_in[5];
    const float* Wv    = (const float*)d_in[6];
    const float* bv    = (const float*)d_in[7];
    const float* Wo    = (const float*)d_in[8];
    const float* bo    = (const float*)d_in[9];
    const float* erk   = (const float*)d_in[10];
    const float* erv   = (const float*)d_in[11];

    // workspace (bf16): xt@0 (8MB), Wh@8M (2MB), qh@10M, kh@18M, vt@26M,
    // yf@34M (8MB each), ervt@44040192 (20480B), erkb@44060672 (16512B)
    const size_t need = 44077184;
    if (ws_size < need) return;
    u16* xt   = (u16*)d_ws;
    u16* Wh   = (u16*)((char*)d_ws + 8388608);
    u16* qh   = (u16*)((char*)d_ws + 10485760);
    u16* kh   = (u16*)((char*)d_ws + 18874368);
    u16* vt   = (u16*)((char*)d_ws + 27262976);
    u16* yf   = (u16*)((char*)d_ws + 35651584);
    u16* ervt = (u16*)((char*)d_ws + 44040192);
    u16* erkb = (u16*)((char*)d_ws + 44060672);
    float* out = (float*)d_out;

    cast_all_kernel<<<dim3(2121), 256, 0, stream>>>(
        x, Wq, Wk, Wv, Wo, erk, erv, xt, Wh, ervt, erkb);
    proj_mfma<<<dim3(T_ / 64, H_, 3 * B_), 256, 0, stream>>>(
        xt, Wh, bq, bk, bv, qh, kh, vt);
    attn_kernel<<<dim3(2048), 256, 0, stream>>>(
        qh, kh, vt, erkb, ervt, xmask, yf);
    outproj_mfma<<<dim3(C_ / 64, B_ * (T_ / 64)), 256, 0, stream>>>(
        yf, Wh + ((size_t)3 << 18), bo, xmask, out);
}